// Round 8
// baseline (1472.330 us; speedup 1.0000x reference)
//
#include <hip/hip_runtime.h>
#include <math.h>

// Problem: B=32, S=2048, H=1024
//   d_out (float): [0] loss | [1..131073) logits (32,2048,2) | [131073..196609) header_mask
//
// R17: schedule surgery closed (R10/R12/R13/R16 all null/regress). The untested
// structural lever: 2 INDEPENDENT blocks/CU. R14 (more waves, same block) was
// null because all waves share the same two barriers -> zero phase diversity;
// m114's measured overlap needs independent wave groups. The 139KB LDS (1
// block/CU) was the epilogue scratch's fault, not the loop's. Fix: single-
// buffered LA+LB (64KB) + 4-pass epilogue through a 34KB red2 alias -> 64KB
// total -> 2 blocks/CU (launch_bounds(512,4), VGPR cap 128 = R9's count).
// Loop: sync(drain) -> reads+MFMA -> sync -> STAGE(next). Per-tile drain is
// exposed per block but the co-resident block computes through it (the m97-
// era 912TF regime). Fragment reads / swizzle / per-acc (kt,kk) order are
// identical to R9 -> bit-identical GEMM; epilogue passes change only a 64-term
// f32 reduction order (<< threshold).

typedef __bf16 bf16x8 __attribute__((ext_vector_type(8)));
typedef float f32x4 __attribute__((ext_vector_type(4)));

struct alignas(16) BF8 { __bf16 h[8]; };
struct alignas(8)  BF4 { __bf16 h[4]; };

typedef const __attribute__((address_space(1))) void glb_void;
typedef __attribute__((address_space(3))) void lds_void;

#define SEQ 2048
#define NB  32
#define HID 1024
#define MROWS (NB * SEQ)          // 65536
#define NKT 16                    // K tiles of 64

// branch-free exact-GELU via A&S 7.1.26 erf approximation (|eps| < 1.5e-7)
__device__ __forceinline__ float gelu_bf(float x) {
    float z  = 0.70710678118f * x;
    float az = fabsf(z);
    float t  = __builtin_amdgcn_rcpf(fmaf(0.3275911f, az, 1.0f));
    float poly = fmaf(fmaf(fmaf(fmaf(1.061405429f, t, -1.453152027f), t,
                         1.421413741f), t, -0.284496736f), t, 0.254829592f) * t;
    float ex = __expf(-az * az);
    float er = copysignf(fmaf(-poly, ex, 1.0f), z);
    return 0.5f * x * (1.0f + er);
}

// ---------------- init logits with b2 (FALLBACK path only) ----------------------
__global__ void sr_init_logits(float* __restrict__ logits, const float* __restrict__ b2) {
    int i = blockIdx.x * 256 + threadIdx.x;
    if (i < MROWS * 2) logits[i] = b2[i & 1];
}

// ---------------- W1 first half -> bf16 -----------------------------------------
__global__ void sr_conv_w1(const float* __restrict__ W1, __bf16* __restrict__ Bt) {
    int gid = blockIdx.x * 256 + threadIdx.x;
    int h = gid >> 8;
    int kb = (gid & 255) * 4;
    float4 v = *(const float4*)&W1[(size_t)h * 2048 + kb];
    BF4 o;
    o.h[0] = (__bf16)v.x; o.h[1] = (__bf16)v.y; o.h[2] = (__bf16)v.z; o.h[3] = (__bf16)v.w;
    *(BF4*)&Bt[(size_t)h * 1024 + kb] = o;
}

// ---------------- enc f32 -> bf16 (Ab) ------------------------------------------
__global__ void sr_conv_enc(const float* __restrict__ enc, __bf16* __restrict__ Ab) {
    size_t i = ((size_t)blockIdx.x * 256 + threadIdx.x) * 8;
    float4 v0 = *(const float4*)&enc[i];
    float4 v1 = *(const float4*)&enc[i + 4];
    BF8 t;
    t.h[0] = (__bf16)v0.x; t.h[1] = (__bf16)v0.y;
    t.h[2] = (__bf16)v0.z; t.h[3] = (__bf16)v0.w;
    t.h[4] = (__bf16)v1.x; t.h[5] = (__bf16)v1.y;
    t.h[6] = (__bf16)v1.z; t.h[7] = (__bf16)v1.w;
    *(BF8*)&Ab[i] = t;
}

// ---------------- formula embedding: index-gather (labels scanned, not enc) -----
__global__ void sr_femb(const float* __restrict__ enc, const int* __restrict__ lab,
                        float* __restrict__ femb) {
    __shared__ int cnt;
    __shared__ int idl[64];                 // plenty: exactly 1 hit/sample by construction
    int b = blockIdx.x;
    int tid = threadIdx.x;
    if (tid == 0) cnt = 0;
    __syncthreads();
    for (int s = tid; s < SEQ; s += 256)
        if (lab[b * SEQ + s] == 2) {
            int p = atomicAdd(&cnt, 1);
            if (p < 64) idl[p] = s;
        }
    __syncthreads();
    float4 a = {0.f, 0.f, 0.f, 0.f};
    int n = cnt < 64 ? cnt : 64;
    for (int i = 0; i < n; ++i) {
        float4 v = *(const float4*)&enc[((size_t)b * SEQ + idl[i]) * HID + tid * 4];
        a.x += v.x; a.y += v.y; a.z += v.z; a.w += v.w;
    }
    *(float4*)&femb[b * HID + tid * 4] = a;
}

// ---------------- fc[b,h] = b1[h] + femb[b,:] . W1[h,1024:2048] -----------------
__global__ void sr_fc(const float* __restrict__ femb, const float* __restrict__ W1,
                      const float* __restrict__ b1, float* __restrict__ fcout) {
    int gw = (blockIdx.x * 256 + threadIdx.x) >> 6;
    int lane = threadIdx.x & 63;
    for (int i = 0; i < 16; ++i) {
        int d = gw * 16 + i;
        int b = d >> 10, h = d & 1023;
        const float* fe = femb + b * HID;
        const float* wr = W1 + (size_t)h * 2048 + 1024;
        float p = 0.f;
        #pragma unroll
        for (int t = 0; t < 16; ++t) {
            int k = lane + t * 64;
            p += fe[k] * wr[k];
        }
        #pragma unroll
        for (int off = 32; off; off >>= 1) p += __shfl_down(p, off);
        if (lane == 0) fcout[d] = p + b1[h];
    }
}

// ---------------- PRIMARY: 256^2 GEMM, single-buffer, 2 blocks/CU ---------------
__global__ __launch_bounds__(512, 4)
void sr_gemm17(const __bf16* __restrict__ Ab, const __bf16* __restrict__ Bt,
               const float* __restrict__ fc, const float* __restrict__ W2,
               float* __restrict__ partg) {
    // 65536 B total: loop uses LA (32 KB) | LB (32 KB), single-buffered;
    // epilogue reuses bytes 0..34815 as red2[128][68] across 4 passes.
    __shared__ __align__(16) unsigned char smem[65536];
    __bf16* LAb = (__bf16*)smem;                    // 16384 bf16 elems (32 KB)
    __bf16* LBb = (__bf16*)(smem + 32768);          // 16384 bf16 elems (32 KB)
    float*  red2 = (float*)smem;                    // [128][68] f32 epilogue scratch

    int bid = blockIdx.x;
    int lgc = (bid & 7) * 128 + (bid >> 3);         // XCD-bijective (1024 % 8 == 0)
    int pm = lgc >> 2, pn = lgc & 3;
    const int row0 = pm * 256, col0 = pn * 256;

    int tid = threadIdx.x;
    int wid = tid >> 6, lane = tid & 63;
    int wr = wid >> 2, wc = wid & 3;
    int l15 = lane & 15, lq = lane >> 4;

    f32x4 acc[2][2][4][2] = {};

    #define STAGE(kt) do {                                                        \
        _Pragma("unroll")                                                         \
        for (int i = 0; i < 4; ++i) {                                             \
            int q = i * 512 + tid;                                                \
            int r = q >> 3, c = q & 7;                                            \
            int sc = (c ^ (r & 7)) * 8 + (kt) * 64;                               \
            __builtin_amdgcn_global_load_lds(                                     \
                (glb_void*)(Ab + (size_t)(row0 + r) * HID + sc),                  \
                (lds_void*)(LAb + q * 8), 16, 0, 0);                              \
            __builtin_amdgcn_global_load_lds(                                     \
                (glb_void*)(Bt + (size_t)(col0 + r) * HID + sc),                  \
                (lds_void*)(LBb + q * 8), 16, 0, 0);                              \
        }                                                                         \
    } while (0)

    STAGE(0);
    for (int kt = 0; kt < NKT; ++kt) {
        __syncthreads();                // RAW: drain this tile's DMA (per-wave
                                        // vmcnt(0) before barrier -> sound)

        bf16x8 bfr[2][2][2];
        #pragma unroll
        for (int qb = 0; qb < 2; ++qb)
            #pragma unroll
            for (int n = 0; n < 2; ++n)
                #pragma unroll
                for (int kk = 0; kk < 2; ++kk) {
                    int r = qb * 128 + wc * 32 + n * 16 + l15;
                    bfr[qb][n][kk] = *(const bf16x8*)
                        &LBb[r * 64 + (((kk * 4 + lq) ^ (r & 7)) * 8)];
                }
        #pragma unroll
        for (int qa = 0; qa < 2; ++qa) {
            bf16x8 af[4][2];
            #pragma unroll
            for (int m = 0; m < 4; ++m)
                #pragma unroll
                for (int kk = 0; kk < 2; ++kk) {
                    int r = qa * 128 + wr * 64 + m * 16 + l15;
                    af[m][kk] = *(const bf16x8*)
                        &LAb[r * 64 + (((kk * 4 + lq) ^ (r & 7)) * 8)];
                }
            #pragma unroll
            for (int qb = 0; qb < 2; ++qb)
                #pragma unroll
                for (int m = 0; m < 4; ++m)
                    #pragma unroll
                    for (int n = 0; n < 2; ++n)
                        #pragma unroll
                        for (int kk = 0; kk < 2; ++kk)
                            acc[qa][qb][m][n] = __builtin_amdgcn_mfma_f32_16x16x32_bf16(
                                af[m][kk], bfr[qb][n][kk], acc[qa][qb][m][n], 0, 0, 0);
        }

        __syncthreads();                // WAR: all LDS reads done before overwrite
        if (kt + 1 < NKT) STAGE(kt + 1);
    }
    #undef STAGE
    // loop exits right after a __syncthreads(): red2 aliasing is safe.

    // ---- epilogue: 4 passes through red2[128][68] (rows 64/pass) ----------------
    int b = row0 >> 11;
    float fcv[2][2], w2a[2][2], w2b[2][2];
    #pragma unroll
    for (int qb = 0; qb < 2; ++qb)
        #pragma unroll
        for (int n = 0; n < 2; ++n) {
            int h = col0 + qb * 128 + wc * 32 + n * 16 + l15;
            fcv[qb][n] = fc[b * HID + h];
            w2a[qb][n] = W2[h];
            w2b[qb][n] = W2[HID + h];
        }
    int e = wc * 16 + l15;                  // 0..63: h-subgroup this lane covers

    // pass (QA, WSEL): waves with wr==WSEL write rows [QA*128+WSEL*64, +64)
    #define EPIPASS(QA, WSEL) do {                                                \
        if (wr == (WSEL)) {                                                       \
            _Pragma("unroll")                                                     \
            for (int m = 0; m < 4; ++m)                                           \
                _Pragma("unroll")                                                 \
                for (int j = 0; j < 4; ++j) {                                     \
                    int rl = m * 16 + lq * 4 + j;      /* 0..63 local row */      \
                    float p0 = 0.f, p1 = 0.f;                                     \
                    _Pragma("unroll")                                             \
                    for (int qb = 0; qb < 2; ++qb)                                \
                        _Pragma("unroll")                                         \
                        for (int n = 0; n < 2; ++n) {                             \
                            float g = gelu_bf(acc[QA][qb][m][n][j] + fcv[qb][n]); \
                            p0 += g * w2a[qb][n];                                 \
                            p1 += g * w2b[qb][n];                                 \
                        }                                                         \
                    red2[(rl * 2 + 0) * 68 + e] = p0;                             \
                    red2[(rl * 2 + 1) * 68 + e] = p1;                             \
                }                                                                 \
        }                                                                         \
        __syncthreads();                                                          \
        if (tid < 256) {                                                          \
            int rc = tid >> 1, half = tid & 1;       /* rc: row_l*2+c */          \
            const f32x4* rp = (const f32x4*)&red2[rc * 68 + half * 32];           \
            f32x4 sv = rp[0] + rp[1] + rp[2] + rp[3]                              \
                     + rp[4] + rp[5] + rp[6] + rp[7];                             \
            float s = sv[0] + sv[1] + sv[2] + sv[3];                              \
            s += __shfl_xor(s, 1);                                                \
            if (half == 0) {                                                      \
                int rowg = row0 + (QA) * 128 + (WSEL) * 64 + (rc >> 1);           \
                partg[((size_t)pn * MROWS + rowg) * 2 + (rc & 1)] = s;            \
            }                                                                     \
        }                                                                         \
        __syncthreads();                                                          \
    } while (0)

    EPIPASS(0, 0);
    EPIPASS(0, 1);
    EPIPASS(1, 0);
    EPIPASS(1, 1);
    #undef EPIPASS
}

// ---------------- FALLBACK GEMM (atomics path, used only if ws too small) -------
__global__ __launch_bounds__(256, 2)
void sr_gemm_fused(const float* __restrict__ enc, const __bf16* __restrict__ Bt,
                   const float* __restrict__ fc, const float* __restrict__ W2,
                   float* __restrict__ logits) {
    __shared__ __bf16 As[128 * 64];
    __shared__ __bf16 Bs[128 * 64];

    int bid = blockIdx.x;
    int logical = (bid & 7) * 512 + (bid >> 3);
    int pm = logical >> 3;
    int pn = logical & 7;

    int tid = threadIdx.x;
    int wid = tid >> 6, lane = tid & 63;
    int wm = wid >> 1, wn = wid & 1;

    const int row0 = pm * 128;
    const int col0 = pn * 128;

    f32x4 acc[4][4] = {};

    for (int kt = 0; kt < 16; ++kt) {
        int k0 = kt * 64;
        #pragma unroll
        for (int i = 0; i < 4; ++i) {
            int q = i * 256 + tid;
            int r = q >> 3;
            int cb = (q & 7) * 8;
            const __bf16* src = Bt + (size_t)(col0 + r) * 1024 + k0 + cb;
            __builtin_amdgcn_global_load_lds((glb_void*)src, (lds_void*)&Bs[q * 8], 16, 0, 0);
        }
        #pragma unroll
        for (int pp = 0; pp < 4; ++pp) {
            int e = pp * 2048 + tid * 8;
            int r = e >> 6, c = e & 63;
            const float* src = enc + (size_t)(row0 + r) * 1024 + k0 + c;
            float4 f0 = *(const float4*)src;
            float4 f1 = *(const float4*)(src + 4);
            BF8 t;
            t.h[0] = (__bf16)f0.x; t.h[1] = (__bf16)f0.y;
            t.h[2] = (__bf16)f0.z; t.h[3] = (__bf16)f0.w;
            t.h[4] = (__bf16)f1.x; t.h[5] = (__bf16)f1.y;
            t.h[6] = (__bf16)f1.z; t.h[7] = (__bf16)f1.w;
            *(BF8*)&As[r * 64 + c] = t;
        }
        __syncthreads();
        int lrow = lane & 15;
        int ak = (lane >> 4) * 8;
        #pragma unroll
        for (int kk = 0; kk < 2; ++kk) {
            bf16x8 a[4], b[4];
            #pragma unroll
            for (int m = 0; m < 4; ++m)
                a[m] = *(const bf16x8*)&As[(wm * 64 + m * 16 + lrow) * 64 + kk * 32 + ak];
            #pragma unroll
            for (int n = 0; n < 4; ++n)
                b[n] = *(const bf16x8*)&Bs[(wn * 64 + n * 16 + lrow) * 64 + kk * 32 + ak];
            #pragma unroll
            for (int m = 0; m < 4; ++m)
                #pragma unroll
                for (int n = 0; n < 4; ++n)
                    acc[m][n] = __builtin_amdgcn_mfma_f32_16x16x32_bf16(a[m], b[n], acc[m][n], 0, 0, 0);
        }
        __syncthreads();
    }

    int bidx = row0 >> 11;
    float fcv[4], w2a[4], w2b[4];
    #pragma unroll
    for (int n = 0; n < 4; ++n) {
        int h = col0 + wn * 64 + n * 16 + (lane & 15);
        fcv[n] = fc[bidx * HID + h];
        w2a[n] = W2[h];
        w2b[n] = W2[HID + h];
    }
    #pragma unroll
    for (int m = 0; m < 4; ++m) {
        int rbase = row0 + wm * 64 + m * 16 + (lane >> 4) * 4;
        #pragma unroll
        for (int j = 0; j < 4; ++j) {
            float p0 = 0.f, p1 = 0.f;
            #pragma unroll
            for (int n = 0; n < 4; ++n) {
                float g = gelu_bf(acc[m][n][j] + fcv[n]);
                p0 += g * w2a[n];
                p1 += g * w2b[n];
            }
            #pragma unroll
            for (int off = 1; off < 16; off <<= 1) {
                p0 += __shfl_xor(p0, off);
                p1 += __shfl_xor(p1, off);
            }
            if ((lane & 15) == 0) {
                int rg = rbase + j;
                atomicAdd(&logits[rg * 2 + 0], p0);
                atomicAdd(&logits[rg * 2 + 1], p1);
            }
        }
    }
}

// ---------------- loss from partials: logits = b2 + sum_pn partg; CE ------------
__global__ void sr_loss_pg(const int* __restrict__ lab, const float* __restrict__ partg,
                           const float* __restrict__ b2, float* __restrict__ logits,
                           float* __restrict__ mask_out, float* __restrict__ sl,
                           float* __restrict__ validv) {
    int b = blockIdx.x;
    int tid = threadIdx.x;
    float b20 = b2[0], b21 = b2[1];
    float lsum = 0.f; int lcnt = 0;
    for (int s = tid; s < SEQ; s += 256) {
        size_t row = (size_t)b * SEQ + s;
        float l0 = b20, l1 = b21;
        #pragma unroll
        for (int q = 0; q < 4; ++q) {
            l0 += partg[((size_t)q * MROWS + row) * 2 + 0];
            l1 += partg[((size_t)q * MROWS + row) * 2 + 1];
        }
        logits[row * 2 + 0] = l0;
        logits[row * 2 + 1] = l1;
        int l = lab[row];
        bool hdr = (l == 0) || (l == 1);
        mask_out[row] = hdr ? 1.0f : 0.0f;
        if (hdr) {
            float mx = fmaxf(l0, l1);
            float lse = mx + logf(expf(l0 - mx) + expf(l1 - mx));
            lsum += lse - (l == 0 ? l0 : l1);
            lcnt++;
        }
    }
    #pragma unroll
    for (int off = 32; off; off >>= 1) {
        lsum += __shfl_down(lsum, off);
        lcnt += __shfl_down(lcnt, off);
    }
    __shared__ float wsum[4];
    __shared__ int wcnt[4];
    int wid = tid >> 6, lane = tid & 63;
    if (lane == 0) { wsum[wid] = lsum; wcnt[wid] = lcnt; }
    __syncthreads();
    if (tid == 0) {
        float S = wsum[0] + wsum[1] + wsum[2] + wsum[3];
        int C = wcnt[0] + wcnt[1] + wcnt[2] + wcnt[3];
        sl[b] = (C > 0) ? S / (float)C : 0.0f;
        validv[b] = (C > 0) ? 1.0f : 0.0f;
    }
}

// ---------------- loss reading logits directly (FALLBACK path) ------------------
__global__ void sr_loss(const int* __restrict__ lab, const float* __restrict__ logits,
                        float* __restrict__ mask_out, float* __restrict__ sl,
                        float* __restrict__ validv) {
    int b = blockIdx.x;
    int tid = threadIdx.x;
    float lsum = 0.f; int lcnt = 0;
    for (int s = tid; s < SEQ; s += 256) {
        int l = lab[b * SEQ + s];
        bool hdr = (l == 0) || (l == 1);
        mask_out[b * SEQ + s] = hdr ? 1.0f : 0.0f;
        if (hdr) {
            float l0 = logits[(b * SEQ + s) * 2];
            float l1 = logits[(b * SEQ + s) * 2 + 1];
            float mx = fmaxf(l0, l1);
            float lse = mx + logf(expf(l0 - mx) + expf(l1 - mx));
            lsum += lse - (l == 0 ? l0 : l1);
            lcnt++;
        }
    }
    #pragma unroll
    for (int off = 32; off; off >>= 1) {
        lsum += __shfl_down(lsum, off);
        lcnt += __shfl_down(lcnt, off);
    }
    __shared__ float wsum[4];
    __shared__ int wcnt[4];
    int wid = tid >> 6, lane = tid & 63;
    if (lane == 0) { wsum[wid] = lsum; wcnt[wid] = lcnt; }
    __syncthreads();
    if (tid == 0) {
        float S = wsum[0] + wsum[1] + wsum[2] + wsum[3];
        int C = wcnt[0] + wcnt[1] + wcnt[2] + wcnt[3];
        sl[b] = (C > 0) ? S / (float)C : 0.0f;
        validv[b] = (C > 0) ? 1.0f : 0.0f;
    }
}

__global__ void sr_final(const float* __restrict__ sl, const float* __restrict__ validv,
                         float* __restrict__ out) {
    if (threadIdx.x == 0) {
        float s = 0.f, v = 0.f;
        for (int b = 0; b < NB; ++b) { s += sl[b]; v += validv[b]; }
        out[0] = s / (v + 1e-6f);
    }
}

extern "C" void kernel_launch(void* const* d_in, const int* in_sizes, int n_in,
                              void* d_out, int out_size, void* d_ws, size_t ws_size,
                              hipStream_t stream) {
    const float* enc = (const float*)d_in[0];
    const int*   lab = (const int*)d_in[1];
    const float* W1  = (const float*)d_in[2];
    const float* b1  = (const float*)d_in[3];
    const float* W2  = (const float*)d_in[4];
    const float* b2  = (const float*)d_in[5];

    float* out     = (float*)d_out;
    float* loss    = out;
    float* logits  = out + 1;
    float* maskout = out + 1 + MROWS * 2;

    float* ws     = (float*)d_ws;
    float* femb   = ws;                            // 32768 f32
    float* fc     = ws + 32768;                    // 32768 f32
    float* sl     = ws + 65536;                    // 32
    float* validv = ws + 65568;                    // 32
    float* partg  = ws + 65600;                    // 524288 f32 (2 MB)
    __bf16* Bt    = (__bf16*)(ws + 65600 + 2 * 524288);  // 2 MB
    __bf16* Ab    = Bt + (size_t)HID * HID;              // 134.2 MB

    const size_t need = (65600u + 2u * 524288u) * 4u + (size_t)HID * HID * 2u
                      + (size_t)MROWS * HID * 2u;

    sr_conv_w1<<<1024, 256, 0, stream>>>(W1, Bt);
    sr_femb<<<32, 256, 0, stream>>>(enc, lab, femb);
    sr_fc<<<512, 256, 0, stream>>>(femb, W1, b1, fc);

    if (ws_size >= need) {
        sr_conv_enc<<<32768, 256, 0, stream>>>(enc, Ab);
        sr_gemm17<<<1024, 512, 0, stream>>>(Ab, Bt, fc, W2, partg);
        sr_loss_pg<<<32, 256, 0, stream>>>(lab, partg, b2, logits, maskout, sl, validv);
    } else {
        sr_init_logits<<<512, 256, 0, stream>>>(logits, b2);
        sr_gemm_fused<<<4096, 256, 0, stream>>>(enc, Bt, fc, W2, logits);
        sr_loss<<<32, 256, 0, stream>>>(lab, logits, maskout, sl, validv);
    }

    sr_final<<<1, 64, 0, stream>>>(sl, validv, loss);
}